// Round 7
// baseline (570.815 us; speedup 1.0000x reference)
//
#include <hip/hip_runtime.h>
#include <hip/hip_bf16.h>
#include <math.h>

#define NEG_SLOPE 0.2f
#define CHUNK 1024
#define PACK_SHIFT 22
#define PACK_MASK ((1u << PACK_SHIFT) - 1u)

typedef __attribute__((ext_vector_type(8))) short short8;
typedef __attribute__((ext_vector_type(4))) float f32x4;

__device__ __forceinline__ float leaky(float v) { return v >= 0.f ? v : NEG_SLOPE * v; }

// fp32 -> bf16 RNE (bit trick, finite inputs)
__device__ __forceinline__ short bfr(float f)
{
    union { float f; unsigned u; } v; v.f = f;
    unsigned r = (v.u + 0x7FFFu + ((v.u >> 16) & 1u)) >> 16;
    return (short)r;
}
// bf16 bits -> fp32
__device__ __forceinline__ float b2f(short s)
{
    union { unsigned u; float f; } v; v.u = ((unsigned)(unsigned short)s) << 16;
    return v.f;
}

// fp32 -> OCP e4m3fn (RNE, clamp 448, FTZ-free subnormals)
__device__ __forceinline__ unsigned char enc8(float f)
{
    union { float f; unsigned u; } v; v.f = f;
    unsigned s = (v.u >> 24) & 0x80u;
    v.u &= 0x7FFFFFFFu;
    if (v.f >= 448.f) return (unsigned char)(s | 0x7Eu);       // 448
    if (v.f < 0.015625f) {                                     // subnormal: k * 2^-9
        int mm = (int)rintf(v.f * 512.f);                      // 0..8 (8 carries to 2^-6)
        return (unsigned char)(s | (unsigned)mm);
    }
    unsigned u = v.u + 0x7FFFFu + ((v.u >> 20) & 1u);          // RNE to 3-bit mantissa
    unsigned e = ((u >> 23) & 0xFFu) - 120u;
    unsigned m = (u >> 20) & 7u;
    return (unsigned char)(s | (e << 3) | m);
}

// e4m3fn -> fp32
__device__ __forceinline__ float dec8(unsigned b)
{
#if __has_builtin(__builtin_amdgcn_cvt_f32_fp8)
    return __builtin_amdgcn_cvt_f32_fp8((int)b, 0);
#else
    unsigned s = (b & 0x80u) << 24, em = b & 0x7Fu;
    union { unsigned u; float f; } n; n.u = s | (((em >> 3) + 120u) << 23) | ((em & 7u) << 20);
    union { unsigned u; float f; } t; t.f = (float)em * 0.001953125f; t.u |= s;
    return em >= 8u ? n.f : t.f;
#endif
}

// ---------------- edge dtype detect ----------------
__global__ void detect_kernel(const unsigned* __restrict__ w, int* __restrict__ flag)
{
    __shared__ int anynz;
    if (threadIdx.x == 0) anynz = 0;
    __syncthreads();
    bool nz = false;
#pragma unroll
    for (int j = 0; j < 8; ++j) {
        int idx = 2 * (threadIdx.x + 256 * j) + 1;
        nz |= (w[idx] != 0u);
    }
    if (nz) anynz = 1;
    __syncthreads();
    if (threadIdx.x == 0) *flag = anynz ? 0 : 1;     // 1 => int64 layout
}

// ---------------- weight transpose (bf16) + logit projection vectors ----------------
__global__ void w1t_kernel(const float* __restrict__ W1, short* __restrict__ W1Tb)
{
    int id = blockIdx.x * 256 + threadIdx.x;      // 256*64
    if (id >= 256 * 64) return;
    int k = id >> 6, c = id & 63;
    W1Tb[c * 256 + k] = bfr(W1[id]);
}

// w2a = W2 @ as2, w2d = W2 @ ad2  (64 each); one wave
__global__ void w2ad_kernel(const float* __restrict__ W2, const float* __restrict__ as2,
                            const float* __restrict__ ad2, float* __restrict__ w2a,
                            float* __restrict__ w2d)
{
    int k = threadIdx.x;
    if (k >= 64) return;
    float a = 0.f, d = 0.f;
    for (int c = 0; c < 40; ++c) {
        float w = W2[k * 40 + c];
        a += w * as2[c];
        d += w * ad2[c];
    }
    w2a[k] = a; w2d[k] = d;
}

// ---------------- CSR build (dst-sorted, two-pass bucketed) ----------------
__global__ void zero_kernel(int* __restrict__ deg, int N)
{
    int id = blockIdx.x * 256 + threadIdx.x;
    if (id < N) deg[id] = 0;
}

__global__ void hist_kernel(const unsigned* __restrict__ eraw, const int* __restrict__ flag,
                            int* __restrict__ deg, int E)
{
    int e = blockIdx.x * 256 + threadIdx.x;
    if (e >= E) return;
    int f = *flag;
    int dst = (int)(f ? eraw[2 * (E + e)] : eraw[E + e]);
    atomicAdd(&deg[dst], 1);
}

__global__ void chunksum_kernel(const int* __restrict__ deg, int* __restrict__ csum, int N)
{
    int b = blockIdx.x, t = threadIdx.x;
    int base = b * CHUNK + t * 4;
    int s = 0;
#pragma unroll
    for (int j = 0; j < 4; ++j) { int i = base + j; if (i < N) s += deg[i]; }
#pragma unroll
    for (int off = 1; off < 64; off <<= 1) s += __shfl_xor(s, off);
    __shared__ int wt[4];
    if ((t & 63) == 0) wt[t >> 6] = s;
    __syncthreads();
    if (t == 0) csum[b] = wt[0] + wt[1] + wt[2] + wt[3];
}

// single wave; NB <= 128
__global__ void chunkscan_kernel(const int* __restrict__ csum, int* __restrict__ coff,
                                 int* __restrict__ rowptrN, int NB, int E)
{
    int lane = threadIdx.x;
    int v0 = (lane < NB) ? csum[lane] : 0;
    int v1 = (lane + 64 < NB) ? csum[lane + 64] : 0;
    int s0 = v0;
#pragma unroll
    for (int off = 1; off < 64; off <<= 1) { int u = __shfl_up(s0, off); if (lane >= off) s0 += u; }
    int tot0 = __shfl(s0, 63);
    if (lane < NB) coff[lane] = s0 - v0;
    int s1 = v1;
#pragma unroll
    for (int off = 1; off < 64; off <<= 1) { int u = __shfl_up(s1, off); if (lane >= off) s1 += u; }
    if (lane + 64 < NB) coff[lane + 64] = tot0 + s1 - v1;
    if (lane == 0) *rowptrN = E;
}

__global__ void writeptr_kernel(const int* __restrict__ deg, const int* __restrict__ coff,
                                int* __restrict__ rowptr, int N)
{
    int b = blockIdx.x, t = threadIdx.x;
    int base = b * CHUNK + t * 4;
    int d[4]; int s = 0;
#pragma unroll
    for (int j = 0; j < 4; ++j) { int i = base + j; d[j] = (i < N) ? deg[i] : 0; s += d[j]; }
    int lane = t & 63, wv = t >> 6;
    int incl = s;
#pragma unroll
    for (int off = 1; off < 64; off <<= 1) { int u = __shfl_up(incl, off); if (lane >= off) incl += u; }
    __shared__ int wt[4];
    if (lane == 63) wt[wv] = incl;
    __syncthreads();
    int wbase = 0;
    for (int w = 0; w < wv; ++w) wbase += wt[w];
    int run = wbase + incl - s + coff[b];
#pragma unroll
    for (int j = 0; j < 4; ++j) { int i = base + j; if (i < N) rowptr[i] = run; run += d[j]; }
}

// bucket cursors: bucket b covers dst in [b*64, b*64+64); staging region == CSR region
__global__ void bcur_init_kernel(const int* __restrict__ rowptr, int* __restrict__ bcur, int NB2)
{
    int id = blockIdx.x * 256 + threadIdx.x;
    if (id < NB2) bcur[id] = rowptr[id * 64];
}

// pass 1: append packed (src | dstoff<<22) to the dst's bucket
__global__ void scat1_kernel(const unsigned* __restrict__ eraw, const int* __restrict__ flag,
                             int* __restrict__ bcur, unsigned* __restrict__ stage, int E)
{
    int e = blockIdx.x * 256 + threadIdx.x;
    if (e >= E) return;
    int f = *flag;
    unsigned src = f ? eraw[2 * e] : eraw[e];
    unsigned dst = f ? eraw[2 * (E + e)] : eraw[E + e];
    int pos = atomicAdd(&bcur[dst >> 6], 1);
    stage[pos] = src | ((dst & 63u) << PACK_SHIFT);
}

// pass 2: block per bucket; LDS counters place src at rowptr[dst]+k
__global__ void scat2_kernel(const unsigned* __restrict__ stage, const int* __restrict__ rowptr,
                             int* __restrict__ ssorted, int N)
{
    __shared__ int cnt[64];
    __shared__ int rp[65];
    int b = blockIdx.x, t = threadIdx.x;
    int base = b * 64;
    if (t < 64) cnt[t] = 0;
    if (t < 65) {
        int idx = base + t;
        rp[t] = rowptr[idx < N ? idx : N];
    }
    __syncthreads();
    int beg = rp[0];
    int end = rowptr[(base + 64) < N ? (base + 64) : N];
    for (int i = beg + t; i < end; i += 256) {
        unsigned w = stage[i];
        int src = (int)(w & PACK_MASK);
        int doff = (int)(w >> PACK_SHIFT);
        int k = atomicAdd(&cnt[doff], 1);
        ssorted[rp[doff] + k] = src;
    }
}

// ---------------- GEMM1 (MFMA): h1 = x @ W1 -> fp8 rows + bf16 als + f32 ald ----------
__global__ __launch_bounds__(256) void gemm1_kernel(
    const float* __restrict__ x, const short* __restrict__ W1Tb,
    const float* __restrict__ as1, const float* __restrict__ ad1,
    unsigned char* __restrict__ h1q, short* __restrict__ als1h,
    float* __restrict__ ald1, int N)
{
    const int l = threadIdx.x & 63, wv = threadIdx.x >> 6;
    const int m = l & 15, g = l >> 4;
    const int arow = blockIdx.x * 64 + wv * 16 + m;    // A-frag row
    const bool rv = arow < N;
    const float* xrow = x + (size_t)arow * 256;

    f32x4 acc[4] = {f32x4{0,0,0,0}, f32x4{0,0,0,0}, f32x4{0,0,0,0}, f32x4{0,0,0,0}};

#pragma unroll
    for (int ks = 0; ks < 8; ++ks) {
        const int k0 = ks * 32 + g * 8;
        float xa[8];
        if (rv) {
            float4 v0 = *(const float4*)(xrow + k0);
            float4 v1 = *(const float4*)(xrow + k0 + 4);
            xa[0] = v0.x; xa[1] = v0.y; xa[2] = v0.z; xa[3] = v0.w;
            xa[4] = v1.x; xa[5] = v1.y; xa[6] = v1.z; xa[7] = v1.w;
        } else {
#pragma unroll
            for (int j = 0; j < 8; ++j) xa[j] = 0.f;
        }
        short8 af;
#pragma unroll
        for (int j = 0; j < 8; ++j) af[j] = bfr(xa[j]);
#pragma unroll
        for (int nt = 0; nt < 4; ++nt) {
            short8 bf_ = *(const short8*)(W1Tb + (size_t)(nt * 16 + m) * 256 + k0);
            acc[nt] = __builtin_amdgcn_mfma_f32_16x16x32_bf16(af, bf_, acc[nt], 0, 0, 0);
        }
    }

    // epilogue: fp8 feature store + per-head attention logits
    const int orow0 = blockIdx.x * 64 + wv * 16 + g * 4;
    float a_sv[4], a_dv[4];
#pragma unroll
    for (int nt = 0; nt < 4; ++nt) { a_sv[nt] = as1[nt * 16 + m]; a_dv[nt] = ad1[nt * 16 + m]; }

    float vs[4][4], vd[4][4];
#pragma unroll
    for (int nt = 0; nt < 4; ++nt)
#pragma unroll
        for (int r = 0; r < 4; ++r) {
            vs[nt][r] = acc[nt][r] * a_sv[nt];
            vd[nt][r] = acc[nt][r] * a_dv[nt];
        }
#pragma unroll
    for (int off = 1; off < 8; off <<= 1)
#pragma unroll
        for (int nt = 0; nt < 4; ++nt)
#pragma unroll
            for (int r = 0; r < 4; ++r) {
                vs[nt][r] += __shfl_xor(vs[nt][r], off);
                vd[nt][r] += __shfl_xor(vd[nt][r], off);
            }

#pragma unroll
    for (int nt = 0; nt < 4; ++nt)
#pragma unroll
        for (int r = 0; r < 4; ++r) {
            int row = orow0 + r;
            if (row < N) h1q[row * 64 + nt * 16 + m] = enc8(acc[nt][r]);
        }
    if ((l & 7) == 0) {
        int par = m >> 3;
#pragma unroll
        for (int nt = 0; nt < 4; ++nt)
#pragma unroll
            for (int r = 0; r < 4; ++r) {
                int row = orow0 + r;
                if (row < N) {
                    als1h[row * 8 + 2 * nt + par] = bfr(vs[nt][r]);
                    ald1[row * 8 + 2 * nt + par] = vd[nt][r];
                }
            }
    }
}

// ---------------- agg1: softmax-aggregate + bias + ELU -> xq fp8 + layer2 logits -----
__global__ __launch_bounds__(256) void agg1_kernel(
    const int* __restrict__ rowptr, const int* __restrict__ srcs,
    const unsigned char* __restrict__ h1q, const short* __restrict__ als1h,
    const float* __restrict__ ald1, const float* __restrict__ b1,
    const float* __restrict__ w2a, const float* __restrict__ w2d,
    unsigned char* __restrict__ xq, float* __restrict__ al2s, float* __restrict__ al2d, int N)
{
    int lane = threadIdx.x & 63, wv = threadIdx.x >> 6;
    int n = blockIdx.x * 4 + wv;
    if (n >= N) return;
    int hb = lane >> 3;
    float alsn = b2f(als1h[n * 8 + hb]);
    float aldn = ald1[n * 8 + hb];
    float p = __expf(leaky(alsn + aldn));
    float den = p;
    float acc = p * dec8(h1q[n * 64 + lane]);
    int beg = rowptr[n], end = rowptr[n + 1];
    int i = beg;
    for (; i + 8 <= end; i += 8) {
        int sv = srcs[i + (lane & 7)];
        int sj[8];
#pragma unroll
        for (int j = 0; j < 8; ++j) sj[j] = __shfl(sv, j);
        float hv[8], av[8];
#pragma unroll
        for (int j = 0; j < 8; ++j) {
            hv[j] = dec8(h1q[sj[j] * 64 + lane]);
            av[j] = b2f(als1h[sj[j] * 8 + hb]);
        }
#pragma unroll
        for (int j = 0; j < 8; ++j) {
            float pe = __expf(leaky(av[j] + aldn));
            den += pe;
            acc += pe * hv[j];
        }
    }
    if (i < end) {
        int ii = i + (lane & 7);
        int sv = srcs[ii < end ? ii : end - 1];
        int sj[8];
#pragma unroll
        for (int j = 0; j < 8; ++j) sj[j] = __shfl(sv, j);
        float hv[8], av[8];
#pragma unroll
        for (int j = 0; j < 8; ++j) {
            hv[j] = dec8(h1q[sj[j] * 64 + lane]);
            av[j] = b2f(als1h[sj[j] * 8 + hb]);
        }
#pragma unroll
        for (int j = 0; j < 8; ++j) {
            float pe = (i + j < end) ? __expf(leaky(av[j] + aldn)) : 0.f;
            den += pe;
            acc += pe * hv[j];
        }
    }
    float v = acc / den + b1[lane];
    float xv = v > 0.f ? v : expm1f(v);
    xq[n * 64 + lane] = enc8(xv);
    // layer-2 logits from exact xv: al2s = x2 . (W2 as2), al2d = x2 . (W2 ad2)
    float sa = xv * w2a[lane], sd = xv * w2d[lane];
#pragma unroll
    for (int off = 1; off < 64; off <<= 1) {
        sa += __shfl_xor(sa, off);
        sd += __shfl_xor(sd, off);
    }
    if (lane == 0) { al2s[n] = sa; al2d[n] = sd; }
}

// ---------------- agg2: aggregate x2 (fp8, inline pe) then project W2 + log-softmax --
__global__ __launch_bounds__(256) void agg2_kernel(
    const int* __restrict__ rowptr, const int* __restrict__ srcs,
    const unsigned char* __restrict__ xq,
    const float* __restrict__ al2s, const float* __restrict__ al2d,
    const float* __restrict__ W2, const float* __restrict__ b2,
    float* __restrict__ out, int N)
{
    __shared__ float W2s[64][40];
    __shared__ float gx[4][64];
    int t = threadIdx.x;
    for (int id = t; id < 64 * 40; id += 256) W2s[id / 40][id % 40] = W2[id];
    __syncthreads();

    int lane = t & 63, wv = t >> 6;
    int n = blockIdx.x * 4 + wv;
    if (n >= N) return;
    float dn = al2d[n];
    float p = __expf(leaky(al2s[n] + dn));
    float den = p;
    float g = p * dec8(xq[n * 64 + lane]);
    int beg = rowptr[n], end = rowptr[n + 1];
    int i = beg;
    for (; i + 8 <= end; i += 8) {
        int sv = srcs[i + (lane & 7)];
        int sj[8];
#pragma unroll
        for (int j = 0; j < 8; ++j) sj[j] = __shfl(sv, j);
        float hv[8], av[8];
#pragma unroll
        for (int j = 0; j < 8; ++j) {
            hv[j] = dec8(xq[sj[j] * 64 + lane]);
            av[j] = al2s[sj[j]];
        }
#pragma unroll
        for (int j = 0; j < 8; ++j) {
            float pe = __expf(leaky(av[j] + dn));
            den += pe;
            g += pe * hv[j];
        }
    }
    if (i < end) {
        int ii = i + (lane & 7);
        int sv = srcs[ii < end ? ii : end - 1];
        int sj[8];
#pragma unroll
        for (int j = 0; j < 8; ++j) sj[j] = __shfl(sv, j);
        float hv[8], av[8];
#pragma unroll
        for (int j = 0; j < 8; ++j) {
            hv[j] = dec8(xq[sj[j] * 64 + lane]);
            av[j] = al2s[sj[j]];
        }
#pragma unroll
        for (int j = 0; j < 8; ++j) {
            float pe = (i + j < end) ? __expf(leaky(av[j] + dn)) : 0.f;
            den += pe;
            g += pe * hv[j];
        }
    }
    g /= den;
    gx[wv][lane] = g;            // same-wave LDS handoff (ordered within wave)

    bool act = lane < 40;
    float outv = 0.f;
    if (act) {
#pragma unroll 8
        for (int k = 0; k < 64; ++k) outv += gx[wv][k] * W2s[k][lane];
        outv += b2[lane];
    }
    float vv = act ? outv : -INFINITY;
    float m = vv;
#pragma unroll
    for (int off = 1; off < 64; off <<= 1) m = fmaxf(m, __shfl_xor(m, off));
    float e = act ? __expf(vv - m) : 0.f;
    float sum = e;
#pragma unroll
    for (int off = 1; off < 64; off <<= 1) sum += __shfl_xor(sum, off);
    if (act) out[(size_t)n * 40 + lane] = vv - m - logf(sum);
}

extern "C" void kernel_launch(void* const* d_in, const int* in_sizes, int n_in,
                              void* d_out, int out_size, void* d_ws, size_t ws_size,
                              hipStream_t stream)
{
    const float*    x    = (const float*)d_in[0];
    const unsigned* eraw = (const unsigned*)d_in[1];
    const float*    W1   = (const float*)d_in[2];
    const float*    as1  = (const float*)d_in[3];
    const float*    ad1  = (const float*)d_in[4];
    const float*    b1   = (const float*)d_in[5];
    const float*    W2   = (const float*)d_in[6];
    const float*    as2  = (const float*)d_in[7];
    const float*    ad2  = (const float*)d_in[8];
    const float*    b2   = (const float*)d_in[9];
    float* out = (float*)d_out;

    const int N = in_sizes[0] / 256;
    const int E = in_sizes[1] / 2;
    const int NB = (N + CHUNK - 1) / CHUNK;
    const int NB2 = (N + 63) / 64;

    char* ws = (char*)d_ws;
    size_t off = 0;
    auto alloc = [&](size_t bytes) {
        size_t o = off;
        off = (off + bytes + 255) & ~(size_t)255;
        return o;
    };
    int*      ssorted = (int*)     (ws + alloc((size_t)E * 4));
    unsigned* stage   = (unsigned*)(ws + alloc((size_t)E * 4));
    int*      rowptr  = (int*)     (ws + alloc((size_t)(N + 1) * 4));
    int*      deg     = (int*)     (ws + alloc((size_t)N * 4));
    int*      bcur    = (int*)     (ws + alloc((size_t)NB2 * 4));
    int*      csum    = (int*)     (ws + alloc((size_t)NB * 4));
    int*      coff    = (int*)     (ws + alloc((size_t)NB * 4));
    int*      flag    = (int*)     (ws + alloc(256));
    short*    W1Tb    = (short*)   (ws + alloc((size_t)64 * 256 * 2));
    unsigned char* h1q = (unsigned char*)(ws + alloc((size_t)N * 64));
    unsigned char* xq  = (unsigned char*)(ws + alloc((size_t)N * 64));
    short*    als1h   = (short*)   (ws + alloc((size_t)N * 8 * 2));
    float*    ald1    = (float*)   (ws + alloc((size_t)N * 8 * 4));
    float*    al2s    = (float*)   (ws + alloc((size_t)N * 4));
    float*    al2d    = (float*)   (ws + alloc((size_t)N * 4));
    float*    w2a     = (float*)   (ws + alloc(64 * 4));
    float*    w2d     = (float*)   (ws + alloc(64 * 4));

    dim3 B(256);
    detect_kernel<<<1, B, 0, stream>>>(eraw, flag);
    w1t_kernel<<<dim3(64), B, 0, stream>>>(W1, W1Tb);
    w2ad_kernel<<<1, dim3(64), 0, stream>>>(W2, as2, ad2, w2a, w2d);

    // CSR build (dst-sorted, two-pass bucketed scatter)
    zero_kernel<<<dim3((N + 255) / 256), B, 0, stream>>>(deg, N);
    hist_kernel<<<dim3((E + 255) / 256), B, 0, stream>>>(eraw, flag, deg, E);
    chunksum_kernel<<<dim3(NB), B, 0, stream>>>(deg, csum, N);
    chunkscan_kernel<<<1, dim3(64), 0, stream>>>(csum, coff, rowptr + N, NB, E);
    writeptr_kernel<<<dim3(NB), B, 0, stream>>>(deg, coff, rowptr, N);
    bcur_init_kernel<<<dim3((NB2 + 255) / 256), B, 0, stream>>>(rowptr, bcur, NB2);
    scat1_kernel<<<dim3((E + 255) / 256), B, 0, stream>>>(eraw, flag, bcur, stage, E);
    scat2_kernel<<<dim3(NB2), B, 0, stream>>>(stage, rowptr, ssorted, N);

    // layer 1
    gemm1_kernel<<<dim3((N + 63) / 64), B, 0, stream>>>(x, W1Tb, as1, ad1, h1q, als1h, ald1, N);
    agg1_kernel<<<dim3((N + 3) / 4), B, 0, stream>>>(rowptr, ssorted, h1q, als1h, ald1,
                                                     b1, w2a, w2d, xq, al2s, al2d, N);

    // layer 2 (gemm2 folded away; pe computed inline in agg2)
    agg2_kernel<<<dim3((N + 3) / 4), B, 0, stream>>>(rowptr, ssorted, xq,
                                                     al2s, al2d, W2, b2, out, N);
}

// Round 8
// 424.051 us; speedup vs baseline: 1.3461x; 1.3461x over previous
//
#include <hip/hip_runtime.h>
#include <hip/hip_bf16.h>
#include <math.h>

#define NEG_SLOPE 0.2f
#define CHUNK 1024

typedef __attribute__((ext_vector_type(8))) short short8;
typedef __attribute__((ext_vector_type(4))) float f32x4;

__device__ __forceinline__ float leaky(float v) { return v >= 0.f ? v : NEG_SLOPE * v; }

// fp32 -> bf16 RNE (bit trick, finite inputs)
__device__ __forceinline__ short bfr(float f)
{
    union { float f; unsigned u; } v; v.f = f;
    unsigned r = (v.u + 0x7FFFu + ((v.u >> 16) & 1u)) >> 16;
    return (short)r;
}
// bf16 bits -> fp32
__device__ __forceinline__ float b2f(short s)
{
    union { unsigned u; float f; } v; v.u = ((unsigned)(unsigned short)s) << 16;
    return v.f;
}

// fp32 -> OCP e4m3fn (RNE, clamp 448, FTZ-free subnormals)
__device__ __forceinline__ unsigned char enc8(float f)
{
    union { float f; unsigned u; } v; v.f = f;
    unsigned s = (v.u >> 24) & 0x80u;
    v.u &= 0x7FFFFFFFu;
    if (v.f >= 448.f) return (unsigned char)(s | 0x7Eu);       // 448
    if (v.f < 0.015625f) {                                     // subnormal: k * 2^-9
        int mm = (int)rintf(v.f * 512.f);                      // 0..8 (8 carries to 2^-6)
        return (unsigned char)(s | (unsigned)mm);
    }
    unsigned u = v.u + 0x7FFFFu + ((v.u >> 20) & 1u);          // RNE to 3-bit mantissa
    unsigned e = ((u >> 23) & 0xFFu) - 120u;
    unsigned m = (u >> 20) & 7u;
    return (unsigned char)(s | (e << 3) | m);
}

// e4m3fn -> fp32
__device__ __forceinline__ float dec8(unsigned b)
{
#if __has_builtin(__builtin_amdgcn_cvt_f32_fp8)
    return __builtin_amdgcn_cvt_f32_fp8((int)b, 0);
#else
    unsigned s = (b & 0x80u) << 24, em = b & 0x7Fu;
    union { unsigned u; float f; } n; n.u = s | (((em >> 3) + 120u) << 23) | ((em & 7u) << 20);
    union { unsigned u; float f; } t; t.f = (float)em * 0.001953125f; t.u |= s;
    return em >= 8u ? n.f : t.f;
#endif
}

// ---------------- edge dtype detect ----------------
__global__ void detect_kernel(const unsigned* __restrict__ w, int* __restrict__ flag)
{
    __shared__ int anynz;
    if (threadIdx.x == 0) anynz = 0;
    __syncthreads();
    bool nz = false;
#pragma unroll
    for (int j = 0; j < 8; ++j) {
        int idx = 2 * (threadIdx.x + 256 * j) + 1;
        nz |= (w[idx] != 0u);
    }
    if (nz) anynz = 1;
    __syncthreads();
    if (threadIdx.x == 0) *flag = anynz ? 0 : 1;     // 1 => int64 layout
}

// ---------------- weight transpose (bf16) + logit projection vectors ----------------
__global__ void w1t_kernel(const float* __restrict__ W1, short* __restrict__ W1Tb)
{
    int id = blockIdx.x * 256 + threadIdx.x;      // 256*64
    if (id >= 256 * 64) return;
    int k = id >> 6, c = id & 63;
    W1Tb[c * 256 + k] = bfr(W1[id]);
}

// w2a = W2 @ as2, w2d = W2 @ ad2  (64 each); one wave
__global__ void w2ad_kernel(const float* __restrict__ W2, const float* __restrict__ as2,
                            const float* __restrict__ ad2, float* __restrict__ w2a,
                            float* __restrict__ w2d)
{
    int k = threadIdx.x;
    if (k >= 64) return;
    float a = 0.f, d = 0.f;
    for (int c = 0; c < 40; ++c) {
        float w = W2[k * 40 + c];
        a += w * as2[c];
        d += w * ad2[c];
    }
    w2a[k] = a; w2d[k] = d;
}

// ---------------- CSR build (dst-sorted, single-pass low-contention scatter) --------
__global__ void zero2_kernel(int* __restrict__ deg, int* __restrict__ cur, int N)
{
    int id = blockIdx.x * 256 + threadIdx.x;
    if (id < N) { deg[id] = 0; cur[id] = 0; }
}

__global__ void hist_kernel(const unsigned* __restrict__ eraw, const int* __restrict__ flag,
                            int* __restrict__ deg, int E)
{
    int e = blockIdx.x * 256 + threadIdx.x;
    if (e >= E) return;
    int f = *flag;
    int dst = (int)(f ? eraw[2 * (E + e)] : eraw[E + e]);
    atomicAdd(&deg[dst], 1);
}

__global__ void chunksum_kernel(const int* __restrict__ deg, int* __restrict__ csum, int N)
{
    int b = blockIdx.x, t = threadIdx.x;
    int base = b * CHUNK + t * 4;
    int s = 0;
#pragma unroll
    for (int j = 0; j < 4; ++j) { int i = base + j; if (i < N) s += deg[i]; }
#pragma unroll
    for (int off = 1; off < 64; off <<= 1) s += __shfl_xor(s, off);
    __shared__ int wt[4];
    if ((t & 63) == 0) wt[t >> 6] = s;
    __syncthreads();
    if (t == 0) csum[b] = wt[0] + wt[1] + wt[2] + wt[3];
}

// single wave; NB <= 128
__global__ void chunkscan_kernel(const int* __restrict__ csum, int* __restrict__ coff,
                                 int* __restrict__ rowptrN, int NB, int E)
{
    int lane = threadIdx.x;
    int v0 = (lane < NB) ? csum[lane] : 0;
    int v1 = (lane + 64 < NB) ? csum[lane + 64] : 0;
    int s0 = v0;
#pragma unroll
    for (int off = 1; off < 64; off <<= 1) { int u = __shfl_up(s0, off); if (lane >= off) s0 += u; }
    int tot0 = __shfl(s0, 63);
    if (lane < NB) coff[lane] = s0 - v0;
    int s1 = v1;
#pragma unroll
    for (int off = 1; off < 64; off <<= 1) { int u = __shfl_up(s1, off); if (lane >= off) s1 += u; }
    if (lane + 64 < NB) coff[lane + 64] = tot0 + s1 - v1;
    if (lane == 0) *rowptrN = E;
}

__global__ void writeptr_kernel(const int* __restrict__ deg, const int* __restrict__ coff,
                                int* __restrict__ rowptr, int N)
{
    int b = blockIdx.x, t = threadIdx.x;
    int base = b * CHUNK + t * 4;
    int d[4]; int s = 0;
#pragma unroll
    for (int j = 0; j < 4; ++j) { int i = base + j; d[j] = (i < N) ? deg[i] : 0; s += d[j]; }
    int lane = t & 63, wv = t >> 6;
    int incl = s;
#pragma unroll
    for (int off = 1; off < 64; off <<= 1) { int u = __shfl_up(incl, off); if (lane >= off) incl += u; }
    __shared__ int wt[4];
    if (lane == 63) wt[wv] = incl;
    __syncthreads();
    int wbase = 0;
    for (int w = 0; w < wv; ++w) wbase += wt[w];
    int run = wbase + incl - s + coff[b];
#pragma unroll
    for (int j = 0; j < 4; ++j) { int i = base + j; if (i < N) rowptr[i] = run; run += d[j]; }
}

__global__ void scatter_kernel(const unsigned* __restrict__ eraw, const int* __restrict__ flag,
                               const int* __restrict__ rowptr, int* __restrict__ cur,
                               int* __restrict__ ssorted, int E)
{
    int e = blockIdx.x * 256 + threadIdx.x;
    if (e >= E) return;
    int f = *flag;
    int src = (int)(f ? eraw[2 * e] : eraw[e]);
    int dst = (int)(f ? eraw[2 * (E + e)] : eraw[E + e]);
    int k = atomicAdd(&cur[dst], 1);
    ssorted[rowptr[dst] + k] = src;
}

// ---------------- GEMM1 (MFMA): h1 = x @ W1 -> fp8 rows + bf16 als + f32 ald ----------
__global__ __launch_bounds__(256) void gemm1_kernel(
    const float* __restrict__ x, const short* __restrict__ W1Tb,
    const float* __restrict__ as1, const float* __restrict__ ad1,
    unsigned char* __restrict__ h1q, short* __restrict__ als1h,
    float* __restrict__ ald1, int N)
{
    const int l = threadIdx.x & 63, wv = threadIdx.x >> 6;
    const int m = l & 15, g = l >> 4;
    const int arow = blockIdx.x * 64 + wv * 16 + m;    // A-frag row
    const bool rv = arow < N;
    const float* xrow = x + (size_t)arow * 256;

    f32x4 acc[4] = {f32x4{0,0,0,0}, f32x4{0,0,0,0}, f32x4{0,0,0,0}, f32x4{0,0,0,0}};

#pragma unroll
    for (int ks = 0; ks < 8; ++ks) {
        const int k0 = ks * 32 + g * 8;
        float xa[8];
        if (rv) {
            float4 v0 = *(const float4*)(xrow + k0);
            float4 v1 = *(const float4*)(xrow + k0 + 4);
            xa[0] = v0.x; xa[1] = v0.y; xa[2] = v0.z; xa[3] = v0.w;
            xa[4] = v1.x; xa[5] = v1.y; xa[6] = v1.z; xa[7] = v1.w;
        } else {
#pragma unroll
            for (int j = 0; j < 8; ++j) xa[j] = 0.f;
        }
        short8 af;
#pragma unroll
        for (int j = 0; j < 8; ++j) af[j] = bfr(xa[j]);
#pragma unroll
        for (int nt = 0; nt < 4; ++nt) {
            short8 bf_ = *(const short8*)(W1Tb + (size_t)(nt * 16 + m) * 256 + k0);
            acc[nt] = __builtin_amdgcn_mfma_f32_16x16x32_bf16(af, bf_, acc[nt], 0, 0, 0);
        }
    }

    // epilogue: fp8 feature store + per-head attention logits
    const int orow0 = blockIdx.x * 64 + wv * 16 + g * 4;
    float a_sv[4], a_dv[4];
#pragma unroll
    for (int nt = 0; nt < 4; ++nt) { a_sv[nt] = as1[nt * 16 + m]; a_dv[nt] = ad1[nt * 16 + m]; }

    float vs[4][4], vd[4][4];
#pragma unroll
    for (int nt = 0; nt < 4; ++nt)
#pragma unroll
        for (int r = 0; r < 4; ++r) {
            vs[nt][r] = acc[nt][r] * a_sv[nt];
            vd[nt][r] = acc[nt][r] * a_dv[nt];
        }
#pragma unroll
    for (int off = 1; off < 8; off <<= 1)
#pragma unroll
        for (int nt = 0; nt < 4; ++nt)
#pragma unroll
            for (int r = 0; r < 4; ++r) {
                vs[nt][r] += __shfl_xor(vs[nt][r], off);
                vd[nt][r] += __shfl_xor(vd[nt][r], off);
            }

#pragma unroll
    for (int nt = 0; nt < 4; ++nt)
#pragma unroll
        for (int r = 0; r < 4; ++r) {
            int row = orow0 + r;
            if (row < N) h1q[row * 64 + nt * 16 + m] = enc8(acc[nt][r]);
        }
    if ((l & 7) == 0) {
        int par = m >> 3;
#pragma unroll
        for (int nt = 0; nt < 4; ++nt)
#pragma unroll
            for (int r = 0; r < 4; ++r) {
                int row = orow0 + r;
                if (row < N) {
                    als1h[row * 8 + 2 * nt + par] = bfr(vs[nt][r]);
                    ald1[row * 8 + 2 * nt + par] = vd[nt][r];
                }
            }
    }
}

// ---------------- agg1: softmax-aggregate + bias + ELU -> xq fp8 + layer2 logits -----
__global__ __launch_bounds__(256) void agg1_kernel(
    const int* __restrict__ rowptr, const int* __restrict__ srcs,
    const unsigned char* __restrict__ h1q, const short* __restrict__ als1h,
    const float* __restrict__ ald1, const float* __restrict__ b1,
    const float* __restrict__ w2a, const float* __restrict__ w2d,
    unsigned char* __restrict__ xq, float* __restrict__ al2s, float* __restrict__ al2d, int N)
{
    int lane = threadIdx.x & 63, wv = threadIdx.x >> 6;
    int n = blockIdx.x * 4 + wv;
    if (n >= N) return;
    int hb = lane >> 3;
    float alsn = b2f(als1h[n * 8 + hb]);
    float aldn = ald1[n * 8 + hb];
    float p = __expf(leaky(alsn + aldn));
    float den = p;
    float acc = p * dec8(h1q[n * 64 + lane]);
    int beg = rowptr[n], end = rowptr[n + 1];
    int i = beg;
    for (; i + 8 <= end; i += 8) {
        int sv = srcs[i + (lane & 7)];
        int sj[8];
#pragma unroll
        for (int j = 0; j < 8; ++j) sj[j] = __shfl(sv, j);
        float hv[8], av[8];
#pragma unroll
        for (int j = 0; j < 8; ++j) {
            hv[j] = dec8(h1q[sj[j] * 64 + lane]);
            av[j] = b2f(als1h[sj[j] * 8 + hb]);
        }
#pragma unroll
        for (int j = 0; j < 8; ++j) {
            float pe = __expf(leaky(av[j] + aldn));
            den += pe;
            acc += pe * hv[j];
        }
    }
    if (i < end) {
        int ii = i + (lane & 7);
        int sv = srcs[ii < end ? ii : end - 1];
        int sj[8];
#pragma unroll
        for (int j = 0; j < 8; ++j) sj[j] = __shfl(sv, j);
        float hv[8], av[8];
#pragma unroll
        for (int j = 0; j < 8; ++j) {
            hv[j] = dec8(h1q[sj[j] * 64 + lane]);
            av[j] = b2f(als1h[sj[j] * 8 + hb]);
        }
#pragma unroll
        for (int j = 0; j < 8; ++j) {
            float pe = (i + j < end) ? __expf(leaky(av[j] + aldn)) : 0.f;
            den += pe;
            acc += pe * hv[j];
        }
    }
    float v = acc / den + b1[lane];
    float xv = v > 0.f ? v : expm1f(v);
    xq[n * 64 + lane] = enc8(xv);
    // layer-2 logits from exact xv: al2s = x2 . (W2 as2), al2d = x2 . (W2 ad2)
    float sa = xv * w2a[lane], sd = xv * w2d[lane];
#pragma unroll
    for (int off = 1; off < 64; off <<= 1) {
        sa += __shfl_xor(sa, off);
        sd += __shfl_xor(sd, off);
    }
    if (lane == 0) { al2s[n] = sa; al2d[n] = sd; }
}

// ---------------- agg2: aggregate x2 (fp8, inline pe) then project W2 + log-softmax --
__global__ __launch_bounds__(256) void agg2_kernel(
    const int* __restrict__ rowptr, const int* __restrict__ srcs,
    const unsigned char* __restrict__ xq,
    const float* __restrict__ al2s, const float* __restrict__ al2d,
    const float* __restrict__ W2, const float* __restrict__ b2,
    float* __restrict__ out, int N)
{
    __shared__ float W2s[64][40];
    __shared__ float gx[4][64];
    int t = threadIdx.x;
    for (int id = t; id < 64 * 40; id += 256) W2s[id / 40][id % 40] = W2[id];
    __syncthreads();

    int lane = t & 63, wv = t >> 6;
    int n = blockIdx.x * 4 + wv;
    if (n >= N) return;
    float dn = al2d[n];
    float p = __expf(leaky(al2s[n] + dn));
    float den = p;
    float g = p * dec8(xq[n * 64 + lane]);
    int beg = rowptr[n], end = rowptr[n + 1];
    int i = beg;
    for (; i + 8 <= end; i += 8) {
        int sv = srcs[i + (lane & 7)];
        int sj[8];
#pragma unroll
        for (int j = 0; j < 8; ++j) sj[j] = __shfl(sv, j);
        float hv[8], av[8];
#pragma unroll
        for (int j = 0; j < 8; ++j) {
            hv[j] = dec8(xq[sj[j] * 64 + lane]);
            av[j] = al2s[sj[j]];
        }
#pragma unroll
        for (int j = 0; j < 8; ++j) {
            float pe = __expf(leaky(av[j] + dn));
            den += pe;
            g += pe * hv[j];
        }
    }
    if (i < end) {
        int ii = i + (lane & 7);
        int sv = srcs[ii < end ? ii : end - 1];
        int sj[8];
#pragma unroll
        for (int j = 0; j < 8; ++j) sj[j] = __shfl(sv, j);
        float hv[8], av[8];
#pragma unroll
        for (int j = 0; j < 8; ++j) {
            hv[j] = dec8(xq[sj[j] * 64 + lane]);
            av[j] = al2s[sj[j]];
        }
#pragma unroll
        for (int j = 0; j < 8; ++j) {
            float pe = (i + j < end) ? __expf(leaky(av[j] + dn)) : 0.f;
            den += pe;
            g += pe * hv[j];
        }
    }
    g /= den;
    gx[wv][lane] = g;            // same-wave LDS handoff (ordered within wave)

    bool act = lane < 40;
    float outv = 0.f;
    if (act) {
#pragma unroll 8
        for (int k = 0; k < 64; ++k) outv += gx[wv][k] * W2s[k][lane];
        outv += b2[lane];
    }
    float vv = act ? outv : -INFINITY;
    float m = vv;
#pragma unroll
    for (int off = 1; off < 64; off <<= 1) m = fmaxf(m, __shfl_xor(m, off));
    float e = act ? __expf(vv - m) : 0.f;
    float sum = e;
#pragma unroll
    for (int off = 1; off < 64; off <<= 1) sum += __shfl_xor(sum, off);
    if (act) out[(size_t)n * 40 + lane] = vv - m - logf(sum);
}

extern "C" void kernel_launch(void* const* d_in, const int* in_sizes, int n_in,
                              void* d_out, int out_size, void* d_ws, size_t ws_size,
                              hipStream_t stream)
{
    const float*    x    = (const float*)d_in[0];
    const unsigned* eraw = (const unsigned*)d_in[1];
    const float*    W1   = (const float*)d_in[2];
    const float*    as1  = (const float*)d_in[3];
    const float*    ad1  = (const float*)d_in[4];
    const float*    b1   = (const float*)d_in[5];
    const float*    W2   = (const float*)d_in[6];
    const float*    as2  = (const float*)d_in[7];
    const float*    ad2  = (const float*)d_in[8];
    const float*    b2   = (const float*)d_in[9];
    float* out = (float*)d_out;

    const int N = in_sizes[0] / 256;
    const int E = in_sizes[1] / 2;
    const int NB = (N + CHUNK - 1) / CHUNK;

    char* ws = (char*)d_ws;
    size_t off = 0;
    auto alloc = [&](size_t bytes) {
        size_t o = off;
        off = (off + bytes + 255) & ~(size_t)255;
        return o;
    };
    int*      ssorted = (int*)     (ws + alloc((size_t)E * 4));
    int*      rowptr  = (int*)     (ws + alloc((size_t)(N + 1) * 4));
    int*      deg     = (int*)     (ws + alloc((size_t)N * 4));
    int*      cur     = (int*)     (ws + alloc((size_t)N * 4));
    int*      csum    = (int*)     (ws + alloc((size_t)NB * 4));
    int*      coff    = (int*)     (ws + alloc((size_t)NB * 4));
    int*      flag    = (int*)     (ws + alloc(256));
    short*    W1Tb    = (short*)   (ws + alloc((size_t)64 * 256 * 2));
    unsigned char* h1q = (unsigned char*)(ws + alloc((size_t)N * 64));
    unsigned char* xq  = (unsigned char*)(ws + alloc((size_t)N * 64));
    short*    als1h   = (short*)   (ws + alloc((size_t)N * 8 * 2));
    float*    ald1    = (float*)   (ws + alloc((size_t)N * 8 * 4));
    float*    al2s    = (float*)   (ws + alloc((size_t)N * 4));
    float*    al2d    = (float*)   (ws + alloc((size_t)N * 4));
    float*    w2a     = (float*)   (ws + alloc(64 * 4));
    float*    w2d     = (float*)   (ws + alloc(64 * 4));

    dim3 B(256);
    detect_kernel<<<1, B, 0, stream>>>(eraw, flag);
    w1t_kernel<<<dim3(64), B, 0, stream>>>(W1, W1Tb);
    w2ad_kernel<<<1, dim3(64), 0, stream>>>(W2, as2, ad2, w2a, w2d);

    // CSR build (dst-sorted, single-pass scatter, low-contention per-dst cursors)
    zero2_kernel<<<dim3((N + 255) / 256), B, 0, stream>>>(deg, cur, N);
    hist_kernel<<<dim3((E + 255) / 256), B, 0, stream>>>(eraw, flag, deg, E);
    chunksum_kernel<<<dim3(NB), B, 0, stream>>>(deg, csum, N);
    chunkscan_kernel<<<1, dim3(64), 0, stream>>>(csum, coff, rowptr + N, NB, E);
    writeptr_kernel<<<dim3(NB), B, 0, stream>>>(deg, coff, rowptr, N);
    scatter_kernel<<<dim3((E + 255) / 256), B, 0, stream>>>(eraw, flag, rowptr, cur, ssorted, E);

    // layer 1
    gemm1_kernel<<<dim3((N + 63) / 64), B, 0, stream>>>(x, W1Tb, as1, ad1, h1q, als1h, ald1, N);
    agg1_kernel<<<dim3((N + 3) / 4), B, 0, stream>>>(rowptr, ssorted, h1q, als1h, ald1,
                                                     b1, w2a, w2d, xq, al2s, al2d, N);

    // layer 2 (gemm2 folded away; pe computed inline in agg2)
    agg2_kernel<<<dim3((N + 3) / 4), B, 0, stream>>>(rowptr, ssorted, xq,
                                                     al2s, al2d, W2, b2, out, N);
}

// Round 9
// 318.393 us; speedup vs baseline: 1.7928x; 1.3318x over previous
//
#include <hip/hip_runtime.h>
#include <hip/hip_bf16.h>
#include <math.h>

#define NEG_SLOPE 0.2f
#define CHUNK 1024

typedef __attribute__((ext_vector_type(8))) short short8;
typedef __attribute__((ext_vector_type(4))) float f32x4;

__device__ __forceinline__ float leaky(float v) { return v >= 0.f ? v : NEG_SLOPE * v; }

// fp32 -> bf16 RNE (bit trick, finite inputs)
__device__ __forceinline__ short bfr(float f)
{
    union { float f; unsigned u; } v; v.f = f;
    unsigned r = (v.u + 0x7FFFu + ((v.u >> 16) & 1u)) >> 16;
    return (short)r;
}
// bf16 bits -> fp32
__device__ __forceinline__ float b2f(short s)
{
    union { unsigned u; float f; } v; v.u = ((unsigned)(unsigned short)s) << 16;
    return v.f;
}

// fp32 -> OCP e4m3fn (RNE, clamp 448, FTZ-free subnormals)
__device__ __forceinline__ unsigned char enc8(float f)
{
    union { float f; unsigned u; } v; v.f = f;
    unsigned s = (v.u >> 24) & 0x80u;
    v.u &= 0x7FFFFFFFu;
    if (v.f >= 448.f) return (unsigned char)(s | 0x7Eu);       // 448
    if (v.f < 0.015625f) {                                     // subnormal: k * 2^-9
        int mm = (int)rintf(v.f * 512.f);                      // 0..8 (8 carries to 2^-6)
        return (unsigned char)(s | (unsigned)mm);
    }
    unsigned u = v.u + 0x7FFFFu + ((v.u >> 20) & 1u);          // RNE to 3-bit mantissa
    unsigned e = ((u >> 23) & 0xFFu) - 120u;
    unsigned m = (u >> 20) & 7u;
    return (unsigned char)(s | (e << 3) | m);
}

// e4m3fn -> fp32
__device__ __forceinline__ float dec8(unsigned b)
{
#if __has_builtin(__builtin_amdgcn_cvt_f32_fp8)
    return __builtin_amdgcn_cvt_f32_fp8((int)b, 0);
#else
    unsigned s = (b & 0x80u) << 24, em = b & 0x7Fu;
    union { unsigned u; float f; } n; n.u = s | (((em >> 3) + 120u) << 23) | ((em & 7u) << 20);
    union { unsigned u; float f; } t; t.f = (float)em * 0.001953125f; t.u |= s;
    return em >= 8u ? n.f : t.f;
#endif
}

// ---------------- edge dtype detect ----------------
__global__ void detect_kernel(const unsigned* __restrict__ w, int* __restrict__ flag)
{
    __shared__ int anynz;
    if (threadIdx.x == 0) anynz = 0;
    __syncthreads();
    bool nz = false;
#pragma unroll
    for (int j = 0; j < 8; ++j) {
        int idx = 2 * (threadIdx.x + 256 * j) + 1;
        nz |= (w[idx] != 0u);
    }
    if (nz) anynz = 1;
    __syncthreads();
    if (threadIdx.x == 0) *flag = anynz ? 0 : 1;     // 1 => int64 layout
}

// ---------------- weight transpose (bf16) + logit projection vectors ----------------
__global__ void w1t_kernel(const float* __restrict__ W1, short* __restrict__ W1Tb)
{
    int id = blockIdx.x * 256 + threadIdx.x;      // 256*64
    if (id >= 256 * 64) return;
    int k = id >> 6, c = id & 63;
    W1Tb[c * 256 + k] = bfr(W1[id]);
}

// w2a = W2 @ as2, w2d = W2 @ ad2  (64 each); one wave
__global__ void w2ad_kernel(const float* __restrict__ W2, const float* __restrict__ as2,
                            const float* __restrict__ ad2, float* __restrict__ w2a,
                            float* __restrict__ w2d)
{
    int k = threadIdx.x;
    if (k >= 64) return;
    float a = 0.f, d = 0.f;
    for (int c = 0; c < 40; ++c) {
        float w = W2[k * 40 + c];
        a += w * as2[c];
        d += w * ad2[c];
    }
    w2a[k] = a; w2d[k] = d;
}

// ---------------- CSR build: poscnt (hist folded in) -> scan -> place ----------------
__global__ void zero_kernel(int* __restrict__ cur, int N)
{
    int id = blockIdx.x * 256 + threadIdx.x;
    if (id < N) cur[id] = 0;
}

// per-edge: reserve slot within dst segment; cur becomes deg; stageK coalesced
__global__ void poscnt_kernel(const unsigned* __restrict__ eraw, const int* __restrict__ flag,
                              int* __restrict__ cur, int* __restrict__ stageK, int E)
{
    int e = blockIdx.x * 256 + threadIdx.x;
    if (e >= E) return;
    int f = *flag;
    int dst = (int)(f ? eraw[2 * (E + e)] : eraw[E + e]);
    stageK[e] = atomicAdd(&cur[dst], 1);
}

__global__ void chunksum_kernel(const int* __restrict__ deg, int* __restrict__ csum, int N)
{
    int b = blockIdx.x, t = threadIdx.x;
    int base = b * CHUNK + t * 4;
    int s = 0;
#pragma unroll
    for (int j = 0; j < 4; ++j) { int i = base + j; if (i < N) s += deg[i]; }
#pragma unroll
    for (int off = 1; off < 64; off <<= 1) s += __shfl_xor(s, off);
    __shared__ int wt[4];
    if ((t & 63) == 0) wt[t >> 6] = s;
    __syncthreads();
    if (t == 0) csum[b] = wt[0] + wt[1] + wt[2] + wt[3];
}

// single wave; NB <= 128
__global__ void chunkscan_kernel(const int* __restrict__ csum, int* __restrict__ coff,
                                 int* __restrict__ rowptrN, int NB, int E)
{
    int lane = threadIdx.x;
    int v0 = (lane < NB) ? csum[lane] : 0;
    int v1 = (lane + 64 < NB) ? csum[lane + 64] : 0;
    int s0 = v0;
#pragma unroll
    for (int off = 1; off < 64; off <<= 1) { int u = __shfl_up(s0, off); if (lane >= off) s0 += u; }
    int tot0 = __shfl(s0, 63);
    if (lane < NB) coff[lane] = s0 - v0;
    int s1 = v1;
#pragma unroll
    for (int off = 1; off < 64; off <<= 1) { int u = __shfl_up(s1, off); if (lane >= off) s1 += u; }
    if (lane + 64 < NB) coff[lane + 64] = tot0 + s1 - v1;
    if (lane == 0) *rowptrN = E;
}

__global__ void writeptr_kernel(const int* __restrict__ deg, const int* __restrict__ coff,
                                int* __restrict__ rowptr, int N)
{
    int b = blockIdx.x, t = threadIdx.x;
    int base = b * CHUNK + t * 4;
    int d[4]; int s = 0;
#pragma unroll
    for (int j = 0; j < 4; ++j) { int i = base + j; d[j] = (i < N) ? deg[i] : 0; s += d[j]; }
    int lane = t & 63, wv = t >> 6;
    int incl = s;
#pragma unroll
    for (int off = 1; off < 64; off <<= 1) { int u = __shfl_up(incl, off); if (lane >= off) incl += u; }
    __shared__ int wt[4];
    if (lane == 63) wt[wv] = incl;
    __syncthreads();
    int wbase = 0;
    for (int w = 0; w < wv; ++w) wbase += wt[w];
    int run = wbase + incl - s + coff[b];
#pragma unroll
    for (int j = 0; j < 4; ++j) { int i = base + j; if (i < N) rowptr[i] = run; run += d[j]; }
}

// place: no atomic; one random store per edge
__global__ void place_kernel(const unsigned* __restrict__ eraw, const int* __restrict__ flag,
                             const int* __restrict__ rowptr, const int* __restrict__ stageK,
                             int* __restrict__ ssorted, int E)
{
    int e = blockIdx.x * 256 + threadIdx.x;
    if (e >= E) return;
    int f = *flag;
    int src = (int)(f ? eraw[2 * e] : eraw[e]);
    int dst = (int)(f ? eraw[2 * (E + e)] : eraw[E + e]);
    ssorted[rowptr[dst] + stageK[e]] = src;
}

// ---------------- GEMM1 (MFMA): h1 = x @ W1 -> fp8 rows + bf16 als + f32 ald ----------
__global__ __launch_bounds__(256) void gemm1_kernel(
    const float* __restrict__ x, const short* __restrict__ W1Tb,
    const float* __restrict__ as1, const float* __restrict__ ad1,
    unsigned char* __restrict__ h1q, short* __restrict__ als1h,
    float* __restrict__ ald1, int N)
{
    const int l = threadIdx.x & 63, wv = threadIdx.x >> 6;
    const int m = l & 15, g = l >> 4;
    const int arow = blockIdx.x * 64 + wv * 16 + m;    // A-frag row
    const bool rv = arow < N;
    const float* xrow = x + (size_t)arow * 256;

    f32x4 acc[4] = {f32x4{0,0,0,0}, f32x4{0,0,0,0}, f32x4{0,0,0,0}, f32x4{0,0,0,0}};

#pragma unroll
    for (int ks = 0; ks < 8; ++ks) {
        const int k0 = ks * 32 + g * 8;
        float xa[8];
        if (rv) {
            float4 v0 = *(const float4*)(xrow + k0);
            float4 v1 = *(const float4*)(xrow + k0 + 4);
            xa[0] = v0.x; xa[1] = v0.y; xa[2] = v0.z; xa[3] = v0.w;
            xa[4] = v1.x; xa[5] = v1.y; xa[6] = v1.z; xa[7] = v1.w;
        } else {
#pragma unroll
            for (int j = 0; j < 8; ++j) xa[j] = 0.f;
        }
        short8 af;
#pragma unroll
        for (int j = 0; j < 8; ++j) af[j] = bfr(xa[j]);
#pragma unroll
        for (int nt = 0; nt < 4; ++nt) {
            short8 bf_ = *(const short8*)(W1Tb + (size_t)(nt * 16 + m) * 256 + k0);
            acc[nt] = __builtin_amdgcn_mfma_f32_16x16x32_bf16(af, bf_, acc[nt], 0, 0, 0);
        }
    }

    // epilogue: fp8 feature store + per-head attention logits
    const int orow0 = blockIdx.x * 64 + wv * 16 + g * 4;
    float a_sv[4], a_dv[4];
#pragma unroll
    for (int nt = 0; nt < 4; ++nt) { a_sv[nt] = as1[nt * 16 + m]; a_dv[nt] = ad1[nt * 16 + m]; }

    float vs[4][4], vd[4][4];
#pragma unroll
    for (int nt = 0; nt < 4; ++nt)
#pragma unroll
        for (int r = 0; r < 4; ++r) {
            vs[nt][r] = acc[nt][r] * a_sv[nt];
            vd[nt][r] = acc[nt][r] * a_dv[nt];
        }
#pragma unroll
    for (int off = 1; off < 8; off <<= 1)
#pragma unroll
        for (int nt = 0; nt < 4; ++nt)
#pragma unroll
            for (int r = 0; r < 4; ++r) {
                vs[nt][r] += __shfl_xor(vs[nt][r], off);
                vd[nt][r] += __shfl_xor(vd[nt][r], off);
            }

#pragma unroll
    for (int nt = 0; nt < 4; ++nt)
#pragma unroll
        for (int r = 0; r < 4; ++r) {
            int row = orow0 + r;
            if (row < N) h1q[row * 64 + nt * 16 + m] = enc8(acc[nt][r]);
        }
    if ((l & 7) == 0) {
        int par = m >> 3;
#pragma unroll
        for (int nt = 0; nt < 4; ++nt)
#pragma unroll
            for (int r = 0; r < 4; ++r) {
                int row = orow0 + r;
                if (row < N) {
                    als1h[row * 8 + 2 * nt + par] = bfr(vs[nt][r]);
                    ald1[row * 8 + 2 * nt + par] = vd[nt][r];
                }
            }
    }
}

// ---------------- agg1: softmax-aggregate + bias + ELU -> xq fp8 + layer2 logits -----
// lane-parallel pe: lane l computes pe for (edge l>>3, head l&7); shfl-broadcast.
__global__ __launch_bounds__(256) void agg1_kernel(
    const int* __restrict__ rowptr, const int* __restrict__ srcs,
    const unsigned char* __restrict__ h1q, const short* __restrict__ als1h,
    const float* __restrict__ ald1, const float* __restrict__ b1,
    const float* __restrict__ w2a, const float* __restrict__ w2d,
    unsigned char* __restrict__ xq, float* __restrict__ al2s, float* __restrict__ al2d, int N)
{
    int lane = threadIdx.x & 63, wv = threadIdx.x >> 6;
    int n = blockIdx.x * 4 + wv;
    if (n >= N) return;
    int hb = lane >> 3;                 // head of this channel (accumulation)
    int hl = lane & 7;                  // head this lane computes pe for
    int el = lane >> 3;                 // edge slot this lane computes pe for
    float aldn = ald1[n * 8 + hb];
    float aldl = ald1[n * 8 + hl];
    float alsn = b2f(als1h[n * 8 + hb]);
    float p = __expf(leaky(alsn + aldn));
    float den = p;
    float acc = p * dec8(h1q[n * 64 + lane]);
    int beg = rowptr[n], end = rowptr[n + 1];
    int i = beg;
    for (; i + 8 <= end; i += 8) {
        int sv = srcs[i + el];
        float avl = b2f(als1h[sv * 8 + hl]);
        float pel = __expf(leaky(avl + aldl));
        int sj[8]; float pj[8];
#pragma unroll
        for (int j = 0; j < 8; ++j) {
            sj[j] = __shfl(sv, j * 8);
            pj[j] = __shfl(pel, j * 8 + hb);
        }
        float hv[8];
#pragma unroll
        for (int j = 0; j < 8; ++j) hv[j] = dec8(h1q[sj[j] * 64 + lane]);
#pragma unroll
        for (int j = 0; j < 8; ++j) { den += pj[j]; acc += pj[j] * hv[j]; }
    }
    if (i < end) {
        int ii = i + el;
        int sv = srcs[ii < end ? ii : end - 1];
        float avl = b2f(als1h[sv * 8 + hl]);
        float pel = (ii < end) ? __expf(leaky(avl + aldl)) : 0.f;
        int sj[8]; float pj[8];
#pragma unroll
        for (int j = 0; j < 8; ++j) {
            sj[j] = __shfl(sv, j * 8);
            pj[j] = __shfl(pel, j * 8 + hb);
        }
        float hv[8];
#pragma unroll
        for (int j = 0; j < 8; ++j) hv[j] = dec8(h1q[sj[j] * 64 + lane]);
#pragma unroll
        for (int j = 0; j < 8; ++j) { den += pj[j]; acc += pj[j] * hv[j]; }
    }
    float v = acc / den + b1[lane];
    float xv = v > 0.f ? v : expm1f(v);
    xq[n * 64 + lane] = enc8(xv);
    // layer-2 logits from exact xv: al2s = x2 . (W2 as2), al2d = x2 . (W2 ad2)
    float sa = xv * w2a[lane], sd = xv * w2d[lane];
#pragma unroll
    for (int off = 1; off < 64; off <<= 1) {
        sa += __shfl_xor(sa, off);
        sd += __shfl_xor(sd, off);
    }
    if (lane == 0) { al2s[n] = sa; al2d[n] = sd; }
}

// ---------------- agg2: aggregate x2 (fp8, lane-parallel pe) + W2 + log-softmax ------
__global__ __launch_bounds__(256) void agg2_kernel(
    const int* __restrict__ rowptr, const int* __restrict__ srcs,
    const unsigned char* __restrict__ xq,
    const float* __restrict__ al2s, const float* __restrict__ al2d,
    const float* __restrict__ W2, const float* __restrict__ b2,
    float* __restrict__ out, int N)
{
    __shared__ float W2s[2560];
    __shared__ float gx[4][64];
    int t = threadIdx.x;
    for (int id = t * 4; id < 2560; id += 1024)
        *(float4*)&W2s[id] = *(const float4*)&W2[id];
    __syncthreads();

    int lane = t & 63, wv = t >> 6;
    int n = blockIdx.x * 4 + wv;
    if (n >= N) return;
    int el = lane & 7;
    float dn = al2d[n];
    float p = __expf(leaky(al2s[n] + dn));
    float den = p;
    float g = p * dec8(xq[n * 64 + lane]);
    int beg = rowptr[n], end = rowptr[n + 1];
    int i = beg;
    for (; i + 8 <= end; i += 8) {
        int sv = srcs[i + el];
        float pel = __expf(leaky(al2s[sv] + dn));
        int sj[8]; float pj[8];
#pragma unroll
        for (int j = 0; j < 8; ++j) { sj[j] = __shfl(sv, j); pj[j] = __shfl(pel, j); }
        float hv[8];
#pragma unroll
        for (int j = 0; j < 8; ++j) hv[j] = dec8(xq[sj[j] * 64 + lane]);
#pragma unroll
        for (int j = 0; j < 8; ++j) { den += pj[j]; g += pj[j] * hv[j]; }
    }
    if (i < end) {
        int ii = i + el;
        int sv = srcs[ii < end ? ii : end - 1];
        float pel = (ii < end) ? __expf(leaky(al2s[sv] + dn)) : 0.f;
        int sj[8]; float pj[8];
#pragma unroll
        for (int j = 0; j < 8; ++j) { sj[j] = __shfl(sv, j); pj[j] = __shfl(pel, j); }
        float hv[8];
#pragma unroll
        for (int j = 0; j < 8; ++j) hv[j] = dec8(xq[sj[j] * 64 + lane]);
#pragma unroll
        for (int j = 0; j < 8; ++j) { den += pj[j]; g += pj[j] * hv[j]; }
    }
    g /= den;
    gx[wv][lane] = g;            // same-wave LDS handoff (ordered within wave)

    bool act = lane < 40;
    float outv = 0.f;
    if (act) {
#pragma unroll 8
        for (int k = 0; k < 64; ++k) outv += gx[wv][k] * W2s[k * 40 + lane];
        outv += b2[lane];
    }
    float vv = act ? outv : -INFINITY;
    float m = vv;
#pragma unroll
    for (int off = 1; off < 64; off <<= 1) m = fmaxf(m, __shfl_xor(m, off));
    float e = act ? __expf(vv - m) : 0.f;
    float sum = e;
#pragma unroll
    for (int off = 1; off < 64; off <<= 1) sum += __shfl_xor(sum, off);
    if (act) out[(size_t)n * 40 + lane] = vv - m - logf(sum);
}

extern "C" void kernel_launch(void* const* d_in, const int* in_sizes, int n_in,
                              void* d_out, int out_size, void* d_ws, size_t ws_size,
                              hipStream_t stream)
{
    const float*    x    = (const float*)d_in[0];
    const unsigned* eraw = (const unsigned*)d_in[1];
    const float*    W1   = (const float*)d_in[2];
    const float*    as1  = (const float*)d_in[3];
    const float*    ad1  = (const float*)d_in[4];
    const float*    b1   = (const float*)d_in[5];
    const float*    W2   = (const float*)d_in[6];
    const float*    as2  = (const float*)d_in[7];
    const float*    ad2  = (const float*)d_in[8];
    const float*    b2   = (const float*)d_in[9];
    float* out = (float*)d_out;

    const int N = in_sizes[0] / 256;
    const int E = in_sizes[1] / 2;
    const int NB = (N + CHUNK - 1) / CHUNK;

    char* ws = (char*)d_ws;
    size_t off = 0;
    auto alloc = [&](size_t bytes) {
        size_t o = off;
        off = (off + bytes + 255) & ~(size_t)255;
        return o;
    };
    int*      ssorted = (int*)     (ws + alloc((size_t)E * 4));
    int*      stageK  = (int*)     (ws + alloc((size_t)E * 4));
    int*      rowptr  = (int*)     (ws + alloc((size_t)(N + 1) * 4));
    int*      cur     = (int*)     (ws + alloc((size_t)N * 4));
    int*      csum    = (int*)     (ws + alloc((size_t)NB * 4));
    int*      coff    = (int*)     (ws + alloc((size_t)NB * 4));
    int*      flag    = (int*)     (ws + alloc(256));
    short*    W1Tb    = (short*)   (ws + alloc((size_t)64 * 256 * 2));
    unsigned char* h1q = (unsigned char*)(ws + alloc((size_t)N * 64));
    unsigned char* xq  = (unsigned char*)(ws + alloc((size_t)N * 64));
    short*    als1h   = (short*)   (ws + alloc((size_t)N * 8 * 2));
    float*    ald1    = (float*)   (ws + alloc((size_t)N * 8 * 4));
    float*    al2s    = (float*)   (ws + alloc((size_t)N * 4));
    float*    al2d    = (float*)   (ws + alloc((size_t)N * 4));
    float*    w2a     = (float*)   (ws + alloc(64 * 4));
    float*    w2d     = (float*)   (ws + alloc(64 * 4));

    dim3 B(256);
    detect_kernel<<<1, B, 0, stream>>>(eraw, flag);
    w1t_kernel<<<dim3(64), B, 0, stream>>>(W1, W1Tb);
    w2ad_kernel<<<1, dim3(64), 0, stream>>>(W2, as2, ad2, w2a, w2d);

    // CSR build: poscnt (atomic slot + deg) -> scan -> place (no atomic)
    zero_kernel<<<dim3((N + 255) / 256), B, 0, stream>>>(cur, N);
    poscnt_kernel<<<dim3((E + 255) / 256), B, 0, stream>>>(eraw, flag, cur, stageK, E);
    chunksum_kernel<<<dim3(NB), B, 0, stream>>>(cur, csum, N);
    chunkscan_kernel<<<1, dim3(64), 0, stream>>>(csum, coff, rowptr + N, NB, E);
    writeptr_kernel<<<dim3(NB), B, 0, stream>>>(cur, coff, rowptr, N);
    place_kernel<<<dim3((E + 255) / 256), B, 0, stream>>>(eraw, flag, rowptr, stageK, ssorted, E);

    // layer 1
    gemm1_kernel<<<dim3((N + 63) / 64), B, 0, stream>>>(x, W1Tb, as1, ad1, h1q, als1h, ald1, N);
    agg1_kernel<<<dim3((N + 3) / 4), B, 0, stream>>>(rowptr, ssorted, h1q, als1h, ald1,
                                                     b1, w2a, w2d, xq, al2s, al2d, N);

    // layer 2 (gemm2 folded away; pe lane-parallel in agg2)
    agg2_kernel<<<dim3((N + 3) / 4), B, 0, stream>>>(rowptr, ssorted, xq,
                                                     al2s, al2d, W2, b2, out, N);
}